// Round 5
// baseline (249.468 us; speedup 1.0000x reference)
//
#include <hip/hip_runtime.h>
#include <hip/hip_cooperative_groups.h>
namespace cg = cooperative_groups;

#define TPB 256
#define PER_THREAD 32
#define CHUNK (TPB * PER_THREAD)   // 8192 elements per chunk
#define MAXG 1024                  // cooperative grid: 4 blocks/CU on 256 CUs

// ---------------------------------------------------------------------------
// Exclusive block-wide scan of one unsigned per thread. Trailing barrier makes
// the LDS buffer immediately reusable by the next call.
// ---------------------------------------------------------------------------
__device__ __forceinline__ unsigned block_excl_scan(unsigned tsum, unsigned* wtot) {
    const int lane = threadIdx.x & 63;
    const int wid  = threadIdx.x >> 6;
    unsigned v = tsum;
#pragma unroll
    for (int off = 1; off < 64; off <<= 1) {
        unsigned u = __shfl_up(v, off, 64);
        if (lane >= off) v += u;
    }
    if (lane == 63) wtot[wid] = v;
    __syncthreads();
    unsigned woff = 0;
    for (int w = 0; w < wid; ++w) woff += wtot[w];
    unsigned r = woff + v - tsum;
    __syncthreads();
    return r;
}

// ---------------------------------------------------------------------------
// Build this thread's 32-bit positivity mask for its PER_THREAD elements.
// ---------------------------------------------------------------------------
__device__ __forceinline__ unsigned build_mask(const float* __restrict__ score,
                                               long tbase, long n) {
    unsigned m = 0;
    if (tbase + PER_THREAD <= n) {
        const float4* s4 = reinterpret_cast<const float4*>(score + tbase);
#pragma unroll
        for (int q = 0; q < PER_THREAD / 4; ++q) {
            float4 v = s4[q];
            m |= ((unsigned)(v.x > 0.f)) << (4 * q + 0);
            m |= ((unsigned)(v.y > 0.f)) << (4 * q + 1);
            m |= ((unsigned)(v.z > 0.f)) << (4 * q + 2);
            m |= ((unsigned)(v.w > 0.f)) << (4 * q + 3);
        }
    } else {
        for (int e = 0; e < PER_THREAD; ++e) {
            long gi = tbase + e;
            if (gi < n && score[gi] > 0.f) m |= (1u << e);
        }
    }
    return m;
}

// ---------------------------------------------------------------------------
// Main per-chunk math (proven absmax==0.0 path from rounds 2-4).
// ---------------------------------------------------------------------------
__device__ __forceinline__ double chunk_acc(const float* __restrict__ predict,
                                            long tbase, long n, unsigned m,
                                            unsigned run, float rcpSumS,
                                            float invS, float Pf) {
    double acc = 0.0;
    if (tbase + PER_THREAD <= n) {
        const float4* p4 = reinterpret_cast<const float4*>(predict + tbase);
#pragma unroll
        for (int q = 0; q < PER_THREAD / 4; ++q) {
            float4 pv4 = p4[q];
            float pv[4] = {pv4.x, pv4.y, pv4.z, pv4.w};
#pragma unroll
            for (int j = 0; j < 4; ++j) {
                const int e = 4 * q + j;
                const bool ispos = (m >> e) & 1u;
                const unsigned newrun = run + (ispos ? 1u : 0u);
                const float p = pv[j] * rcpSumS;
                const float kp1  = (float)(newrun + 1u);
                const float posv = p * __builtin_amdgcn_rcpf(kp1)
                                 - invS * __builtin_amdgcn_rcpf(__log2f(kp1));
                const unsigned mr = (unsigned)(tbase + e + 1) - newrun;
                const float negv  = p * __builtin_amdgcn_rcpf(Pf + (float)mr + 1.0f);
                const float t = ispos ? posv : negv;
                acc += (double)(t * t);
                run = newrun;
            }
        }
    } else {
        for (int e = 0; e < PER_THREAD; ++e) {
            long gi = tbase + e;
            if (gi >= n) break;
            const bool ispos = (m >> e) & 1u;
            const unsigned newrun = run + (ispos ? 1u : 0u);
            const float p = predict[gi] * rcpSumS;
            const float kp1  = (float)(newrun + 1u);
            const float posv = p * __builtin_amdgcn_rcpf(kp1)
                             - invS * __builtin_amdgcn_rcpf(__log2f(kp1));
            const unsigned mr = (unsigned)(gi + 1) - newrun;
            const float negv  = p * __builtin_amdgcn_rcpf(Pf + (float)mr + 1.0f);
            const float t = ispos ? posv : negv;
            acc += (double)(t * t);
            run = newrun;
        }
    }
    return acc;
}

// ---------------------------------------------------------------------------
// Single cooperative kernel: phase1 count (masks stay in registers),
// grid.sync, phase2 compute, grid.sync, phase3 final reduce by block 0.
// Grid-sync fences fire at phase boundaries only (round-3 lesson: staggered
// per-block device fences mid-stream cause an L2 invalidation storm).
// ---------------------------------------------------------------------------
template <int CPB>
__global__ __launch_bounds__(TPB, 4)
void k_fused(const float* __restrict__ predict, const float* __restrict__ score,
             unsigned* __restrict__ chunkCount, double* __restrict__ blockSum,
             float* __restrict__ out, long n, int numChunks) {
    cg::grid_group grid = cg::this_grid();
    const int tid  = threadIdx.x, bid = blockIdx.x;
    const int lane = tid & 63,    wid = tid >> 6;
    const int G = (int)gridDim.x;

    __shared__ unsigned wtot[TPB / 64];
    __shared__ unsigned wsum[TPB / 64];
    __shared__ unsigned wpart[2 * (TPB / 64)];
    __shared__ unsigned s_off, s_P;
    __shared__ double   dsum[TPB / 64];

    // ---- phase 1: masks (registers) + per-chunk counts (global) ----
    unsigned msk[CPB];
#pragma unroll
    for (int i = 0; i < CPB; ++i) {
        const int  c     = bid * CPB + i;
        const long tbase = (long)c * CHUNK + (long)tid * PER_THREAD;
        unsigned m = (c < numChunks) ? build_mask(score, tbase, n) : 0u;
        msk[i] = m;
        unsigned cnt = __popc(m);
#pragma unroll
        for (int off = 32; off > 0; off >>= 1) cnt += __shfl_down(cnt, off, 64);
        if (lane == 0) wsum[wid] = cnt;
        __syncthreads();
        if (tid == 0) {
            unsigned tot = 0;
            for (int w = 0; w < TPB / 64; ++w) tot += wsum[w];
            if (c < numChunks) chunkCount[c] = tot;
        }
        __syncthreads();
    }

    grid.sync();

    // ---- phase 2: per-block offset + global total from chunkCount ----
    unsigned offp = 0, tot = 0;
    for (int j = tid; j < numChunks; j += TPB) {
        unsigned cc = chunkCount[j];
        tot  += cc;
        offp += (j < bid * CPB) ? cc : 0u;
    }
#pragma unroll
    for (int off = 32; off > 0; off >>= 1) {
        offp += __shfl_down(offp, off, 64);
        tot  += __shfl_down(tot,  off, 64);
    }
    if (lane == 0) { wpart[2 * wid] = offp; wpart[2 * wid + 1] = tot; }
    __syncthreads();
    if (tid == 0) {
        unsigned o = 0, t = 0;
        for (int w = 0; w < TPB / 64; ++w) { o += wpart[2 * w]; t += wpart[2 * w + 1]; }
        s_off = o; s_P = t;
    }
    __syncthreads();

    const unsigned P = s_P;
    const float invS = 1.0f / (float)P;                 // s value at positives
    const float sumS = (float)((double)invS * (double)P);
    const float rcpSumS = 1.0f / sumS;
    const float Pf = (float)P;

    unsigned chunkBase = s_off;
    double acc = 0.0;
#pragma unroll
    for (int i = 0; i < CPB; ++i) {
        const int c = bid * CPB + i;
        unsigned cnt  = __popc(msk[i]);
        unsigned excl = block_excl_scan(cnt, wtot);
        if (c < numChunks) {
            const long tbase = (long)c * CHUNK + (long)tid * PER_THREAD;
            acc += chunk_acc(predict, tbase, n, msk[i], chunkBase + excl,
                             rcpSumS, invS, Pf);
            chunkBase += chunkCount[c];   // uniform load, L2 broadcast
        }
    }

    // ---- per-block deterministic reduce ----
#pragma unroll
    for (int off = 32; off > 0; off >>= 1) acc += __shfl_down(acc, off, 64);
    if (lane == 0) dsum[wid] = acc;
    __syncthreads();
    if (tid == 0) {
        double t = 0.0;
        for (int w = 0; w < TPB / 64; ++w) t += dsum[w];
        blockSum[bid] = t;
    }

    grid.sync();

    // ---- phase 3: block 0 final reduce (fixed order => deterministic) ----
    if (bid == 0) {
        double a2 = 0.0;
        for (int j = tid; j < G; j += TPB) a2 += blockSum[j];
#pragma unroll
        for (int off = 32; off > 0; off >>= 1) a2 += __shfl_down(a2, off, 64);
        if (lane == 0) dsum[wid] = a2;
        __syncthreads();
        if (tid == 0) {
            double t = 0.0;
            for (int w = 0; w < TPB / 64; ++w) t += dsum[w];
            out[0] = (float)t;
        }
    }
}

// ===========================================================================
// Fallback path: proven round-4 3-kernel structure (41.9 us), used only if
// the cooperative launch is rejected.
// ===========================================================================
__global__ void k_count(const float* __restrict__ score,
                        unsigned* __restrict__ blockCount,
                        unsigned* __restrict__ mask, long n) {
    const long base  = (long)blockIdx.x * CHUNK;
    const int  tid   = threadIdx.x;
    const long tbase = base + (long)tid * PER_THREAD;
    unsigned m = build_mask(score, tbase, n);
    if (mask) mask[(size_t)blockIdx.x * TPB + tid] = m;
    unsigned cnt = __popc(m);
#pragma unroll
    for (int off = 32; off > 0; off >>= 1) cnt += __shfl_down(cnt, off, 64);
    __shared__ unsigned wsum[TPB / 64];
    const int lane = tid & 63, wid = tid >> 6;
    if (lane == 0) wsum[wid] = cnt;
    __syncthreads();
    if (tid == 0) {
        unsigned tot = 0;
        for (int w = 0; w < TPB / 64; ++w) tot += wsum[w];
        blockCount[blockIdx.x] = tot;
    }
}

__global__ void k_main(const float* __restrict__ predict,
                       const unsigned* __restrict__ mask,
                       const unsigned* __restrict__ blockCount,
                       double* __restrict__ blockSum, long n, int B) {
    const int  tid   = threadIdx.x;
    const int  bid   = blockIdx.x;
    const long tbase = (long)bid * CHUNK + (long)tid * PER_THREAD;
    const int  lane  = tid & 63, wid = tid >> 6;

    __shared__ unsigned wtot[TPB / 64];
    __shared__ unsigned wpart[2 * (TPB / 64)];
    __shared__ unsigned s_off, s_P;
    __shared__ double   dsum[TPB / 64];

    unsigned m = mask[(size_t)bid * TPB + tid];
    unsigned cnt  = __popc(m);
    unsigned excl = block_excl_scan(cnt, wtot);

    unsigned offp = 0, tot = 0;
    for (int j = tid; j < B; j += TPB) {
        unsigned c = blockCount[j];
        tot  += c;
        offp += (j < bid) ? c : 0u;
    }
#pragma unroll
    for (int off = 32; off > 0; off >>= 1) {
        offp += __shfl_down(offp, off, 64);
        tot  += __shfl_down(tot,  off, 64);
    }
    if (lane == 0) { wpart[2 * wid] = offp; wpart[2 * wid + 1] = tot; }
    __syncthreads();
    if (tid == 0) {
        unsigned o = 0, t = 0;
        for (int w = 0; w < TPB / 64; ++w) { o += wpart[2 * w]; t += wpart[2 * w + 1]; }
        s_off = o; s_P = t;
    }
    __syncthreads();

    const unsigned P = s_P;
    const float invS = 1.0f / (float)P;
    const float sumS = (float)((double)invS * (double)P);
    const float rcpSumS = 1.0f / sumS;
    const float Pf = (float)P;

    double acc = chunk_acc(predict, tbase, n, m, s_off + excl, rcpSumS, invS, Pf);

#pragma unroll
    for (int off = 32; off > 0; off >>= 1) acc += __shfl_down(acc, off, 64);
    if (lane == 0) dsum[wid] = acc;
    __syncthreads();
    if (tid == 0) {
        double t = 0.0;
        for (int w = 0; w < TPB / 64; ++w) t += dsum[w];
        blockSum[bid] = t;
    }
}

__global__ void k_final(const double* __restrict__ blockSum,
                        float* __restrict__ out, int B) {
    const int tid = threadIdx.x;
    double acc = 0.0;
    for (int j = tid; j < B; j += TPB) acc += blockSum[j];
#pragma unroll
    for (int off = 32; off > 0; off >>= 1) acc += __shfl_down(acc, off, 64);
    __shared__ double dsum[TPB / 64];
    const int lane = tid & 63, wid = tid >> 6;
    if (lane == 0) dsum[wid] = acc;
    __syncthreads();
    if (tid == 0) {
        double tot = 0.0;
        for (int w = 0; w < TPB / 64; ++w) tot += dsum[w];
        out[0] = (float)tot;
    }
}

extern "C" void kernel_launch(void* const* d_in, const int* in_sizes, int n_in,
                              void* d_out, int out_size, void* d_ws, size_t ws_size,
                              hipStream_t stream) {
    const float* predict = (const float*)d_in[0];
    const float* score   = (const float*)d_in[1];
    float* outp = (float*)d_out;
    long n = (long)in_sizes[0];
    int numChunks = (int)((n + CHUNK - 1) / CHUNK);   // 2048 for N=2^24

    unsigned char* ws = (unsigned char*)d_ws;
    size_t off = 0;
    unsigned* chunkCount = (unsigned*)(ws + off);
    off += ((size_t)numChunks * sizeof(unsigned) + 255) & ~(size_t)255;
    double* blockSum = (double*)(ws + off);
    off += ((size_t)numChunks * sizeof(double) + 255) & ~(size_t)255;
    unsigned* maskBuf = (unsigned*)(ws + off);
    const size_t maskBytes = (size_t)numChunks * TPB * sizeof(unsigned);
    const bool maskFits = (off + maskBytes) <= ws_size;

    // ---- cooperative single-kernel path ----
    int CPB = (numChunks + MAXG - 1) / MAXG;
    const void* fptr = nullptr;
    if      (CPB <= 1) { CPB = 1; fptr = (const void*)&k_fused<1>; }
    else if (CPB <= 2) { CPB = 2; fptr = (const void*)&k_fused<2>; }
    else if (CPB <= 4) { CPB = 4; fptr = (const void*)&k_fused<4>; }
    else if (CPB <= 8) { CPB = 8; fptr = (const void*)&k_fused<8>; }

    if (fptr) {
        int G = (numChunks + CPB - 1) / CPB;
        void* args[7] = {(void*)&predict, (void*)&score, (void*)&chunkCount,
                         (void*)&blockSum, (void*)&outp, (void*)&n,
                         (void*)&numChunks};
        hipError_t e = hipLaunchCooperativeKernel(fptr, dim3(G), dim3(TPB),
                                                  args, 0, stream);
        if (e == hipSuccess) return;
    }

    // ---- fallback: proven 3-kernel path ----
    if (maskFits) {
        k_count<<<numChunks, TPB, 0, stream>>>(score, chunkCount, maskBuf, n);
        k_main<<<numChunks, TPB, 0, stream>>>(predict, maskBuf, chunkCount,
                                              blockSum, n, numChunks);
        k_final<<<1, TPB, 0, stream>>>(blockSum, outp, numChunks);
    }
}

// Round 6
// 76.872 us; speedup vs baseline: 3.2452x; 3.2452x over previous
//
#include <hip/hip_runtime.h>

#define TPB 256
#define PER_THREAD 32
#define CHUNK (TPB * PER_THREAD)   // 8192 elements per block
#define FXSCALE 0x1p60             // fixed-point scale for deterministic sum

// ---------------------------------------------------------------------------
// Exclusive block-wide scan of one unsigned per thread. wtot is LDS[TPB/64].
// ---------------------------------------------------------------------------
__device__ __forceinline__ unsigned block_excl_scan(unsigned tsum, unsigned* wtot) {
    const int lane = threadIdx.x & 63;
    const int wid  = threadIdx.x >> 6;
    unsigned v = tsum;
#pragma unroll
    for (int off = 1; off < 64; off <<= 1) {
        unsigned u = __shfl_up(v, off, 64);
        if (lane >= off) v += u;
    }
    if (lane == 63) wtot[wid] = v;
    __syncthreads();
    unsigned woff = 0;
    for (int w = 0; w < wid; ++w) woff += wtot[w];
    return woff + v - tsum;   // exclusive prefix for this thread
}

__device__ __forceinline__ unsigned build_mask(const float* __restrict__ score,
                                               long tbase, long n) {
    unsigned m = 0;
    if (tbase + PER_THREAD <= n) {
        const float4* s4 = reinterpret_cast<const float4*>(score + tbase);
#pragma unroll
        for (int q = 0; q < PER_THREAD / 4; ++q) {
            float4 v = s4[q];
            m |= ((unsigned)(v.x > 0.f)) << (4 * q + 0);
            m |= ((unsigned)(v.y > 0.f)) << (4 * q + 1);
            m |= ((unsigned)(v.z > 0.f)) << (4 * q + 2);
            m |= ((unsigned)(v.w > 0.f)) << (4 * q + 3);
        }
    } else {
        for (int e = 0; e < PER_THREAD; ++e) {
            long gi = tbase + e;
            if (gi < n && score[gi] > 0.f) m |= (1u << e);
        }
    }
    return m;
}

// ---------------------------------------------------------------------------
// Main per-chunk math (absmax==0.0 proven path, rounds 2-4).
// ---------------------------------------------------------------------------
__device__ __forceinline__ double chunk_acc(const float* __restrict__ predict,
                                            long tbase, long n, unsigned m,
                                            unsigned run, float rcpSumS,
                                            float invS, float Pf) {
    double acc = 0.0;
    if (tbase + PER_THREAD <= n) {
        const float4* p4 = reinterpret_cast<const float4*>(predict + tbase);
#pragma unroll
        for (int q = 0; q < PER_THREAD / 4; ++q) {
            float4 pv4 = p4[q];
            float pv[4] = {pv4.x, pv4.y, pv4.z, pv4.w};
#pragma unroll
            for (int j = 0; j < 4; ++j) {
                const int e = 4 * q + j;
                const bool ispos = (m >> e) & 1u;
                const unsigned newrun = run + (ispos ? 1u : 0u);
                const float p = pv[j] * rcpSumS;
                const float kp1  = (float)(newrun + 1u);
                const float posv = p * __builtin_amdgcn_rcpf(kp1)
                                 - invS * __builtin_amdgcn_rcpf(__log2f(kp1));
                const unsigned mr = (unsigned)(tbase + e + 1) - newrun;
                const float negv  = p * __builtin_amdgcn_rcpf(Pf + (float)mr + 1.0f);
                const float t = ispos ? posv : negv;
                acc += (double)(t * t);
                run = newrun;
            }
        }
    } else {
        for (int e = 0; e < PER_THREAD; ++e) {
            long gi = tbase + e;
            if (gi >= n) break;
            const bool ispos = (m >> e) & 1u;
            const unsigned newrun = run + (ispos ? 1u : 0u);
            const float p = predict[gi] * rcpSumS;
            const float kp1  = (float)(newrun + 1u);
            const float posv = p * __builtin_amdgcn_rcpf(kp1)
                             - invS * __builtin_amdgcn_rcpf(__log2f(kp1));
            const unsigned mr = (unsigned)(gi + 1) - newrun;
            const float negv  = p * __builtin_amdgcn_rcpf(Pf + (float)mr + 1.0f);
            const float t = ispos ? posv : negv;
            acc += (double)(t * t);
            run = newrun;
        }
    }
    return acc;
}

// ---------------------------------------------------------------------------
// Pass 1: masks + per-block counts. Also resets accum/ticket for pass 2
// (kernel boundary orders these plain stores before pass-2 atomics).
// ---------------------------------------------------------------------------
__global__ void k_count(const float* __restrict__ score,
                        unsigned* __restrict__ blockCount,
                        unsigned* __restrict__ mask,
                        unsigned long long* __restrict__ accum,
                        unsigned* __restrict__ ticket, long n) {
    const int  tid   = threadIdx.x;
    const long tbase = (long)blockIdx.x * CHUNK + (long)tid * PER_THREAD;
    if (blockIdx.x == 0 && tid == 0) { *accum = 0ull; *ticket = 0u; }
    unsigned m = build_mask(score, tbase, n);
    if (mask) mask[(size_t)blockIdx.x * TPB + tid] = m;
    unsigned cnt = __popc(m);
#pragma unroll
    for (int off = 32; off > 0; off >>= 1) cnt += __shfl_down(cnt, off, 64);
    __shared__ unsigned wsum[TPB / 64];
    const int lane = tid & 63, wid = tid >> 6;
    if (lane == 0) wsum[wid] = cnt;
    __syncthreads();
    if (tid == 0) {
        unsigned tot = 0;
        for (int w = 0; w < TPB / 64; ++w) tot += wsum[w];
        blockCount[blockIdx.x] = tot;
    }
}

// ---------------------------------------------------------------------------
// Pass 2: offset/P from blockCount (plain loads, written by previous kernel),
// main math, block reduce, then fixed-point u64 atomic accumulate + ticket.
// NO fences anywhere (rounds 3/5 lesson: fences & grid.sync = L2 inv storm).
// Integer accumulation => bit-deterministic final sum in any arrival order.
// ---------------------------------------------------------------------------
template <bool USE_MASK>
__global__ void k_main(const float* __restrict__ predict,
                       const float* __restrict__ score,
                       const unsigned* __restrict__ mask,
                       const unsigned* __restrict__ blockCount,
                       unsigned long long* __restrict__ accum,
                       unsigned* __restrict__ ticket,
                       float* __restrict__ out, long n, int B) {
    const int  tid   = threadIdx.x;
    const int  bid   = blockIdx.x;
    const long tbase = (long)bid * CHUNK + (long)tid * PER_THREAD;
    const int  lane  = tid & 63, wid = tid >> 6;

    __shared__ unsigned wtot[TPB / 64];
    __shared__ unsigned wpart[2 * (TPB / 64)];
    __shared__ unsigned s_off, s_P;
    __shared__ double   dsum[TPB / 64];

    unsigned m = USE_MASK ? mask[(size_t)bid * TPB + tid]
                          : build_mask(score, tbase, n);
    unsigned cnt  = __popc(m);
    unsigned excl = block_excl_scan(cnt, wtot);

    // per-block exclusive offset + global total P from blockCount
    unsigned offp = 0, tot = 0;
    for (int j = tid; j < B; j += TPB) {
        unsigned c = blockCount[j];
        tot  += c;
        offp += (j < bid) ? c : 0u;
    }
#pragma unroll
    for (int off = 32; off > 0; off >>= 1) {
        offp += __shfl_down(offp, off, 64);
        tot  += __shfl_down(tot,  off, 64);
    }
    if (lane == 0) { wpart[2 * wid] = offp; wpart[2 * wid + 1] = tot; }
    __syncthreads();
    if (tid == 0) {
        unsigned o = 0, t = 0;
        for (int w = 0; w < TPB / 64; ++w) { o += wpart[2 * w]; t += wpart[2 * w + 1]; }
        s_off = o; s_P = t;
    }
    __syncthreads();

    const unsigned P = s_P;
    const float invS = 1.0f / (float)P;                 // s value at positives
    const float sumS = (float)((double)invS * (double)P);
    const float rcpSumS = 1.0f / sumS;
    const float Pf = (float)P;

    double acc = chunk_acc(predict, tbase, n, m, s_off + excl, rcpSumS, invS, Pf);

    // deterministic block reduce
#pragma unroll
    for (int off = 32; off > 0; off >>= 1) acc += __shfl_down(acc, off, 64);
    if (lane == 0) dsum[wid] = acc;
    __syncthreads();
    if (tid == 0) {
        double t = 0.0;
        for (int w = 0; w < TPB / 64; ++w) t += dsum[w];
        // fixed-point accumulate: integer adds commute -> deterministic total
        unsigned long long tq = (unsigned long long)(t * FXSCALE);
        unsigned long long oldv = atomicAdd(accum, tq);
        asm volatile("" :: "v"(oldv));   // force completion before ticket add
        unsigned old = atomicAdd(ticket, 1u);
        if (old == (unsigned)B - 1u) {   // last block: read final total
            unsigned long long totq = atomicAdd(accum, 0ull);
            out[0] = (float)((double)totq * (1.0 / FXSCALE));
        }
    }
}

extern "C" void kernel_launch(void* const* d_in, const int* in_sizes, int n_in,
                              void* d_out, int out_size, void* d_ws, size_t ws_size,
                              hipStream_t stream) {
    const float* predict = (const float*)d_in[0];
    const float* score   = (const float*)d_in[1];
    const long n = (long)in_sizes[0];
    const int B = (int)((n + CHUNK - 1) / CHUNK);   // 2048 for N=2^24

    unsigned char* ws = (unsigned char*)d_ws;
    size_t off = 0;
    unsigned* blockCount = (unsigned*)(ws + off); off += (size_t)B * sizeof(unsigned);
    off = (off + 255) & ~(size_t)255;
    unsigned long long* accum = (unsigned long long*)(ws + off);
    unsigned* ticket = (unsigned*)(ws + off + sizeof(unsigned long long));
    off += 256;
    unsigned* maskBuf = (unsigned*)(ws + off);
    const size_t maskBytes = (size_t)B * TPB * sizeof(unsigned);
    const bool useMask = (off + maskBytes) <= ws_size;

    k_count<<<B, TPB, 0, stream>>>(score, blockCount, useMask ? maskBuf : nullptr,
                                   accum, ticket, n);
    if (useMask)
        k_main<true><<<B, TPB, 0, stream>>>(predict, nullptr, maskBuf, blockCount,
                                            accum, ticket, (float*)d_out, n, B);
    else
        k_main<false><<<B, TPB, 0, stream>>>(predict, score, nullptr, blockCount,
                                             accum, ticket, (float*)d_out, n, B);
}

// Round 7
// 35.509 us; speedup vs baseline: 7.0255x; 2.1649x over previous
//
#include <hip/hip_runtime.h>

#define TPB 256
#define PER_THREAD 32
#define CHUNK (TPB * PER_THREAD)     // 8192 elements per block
#define WCHUNK (64 * PER_THREAD)     // 2048 elements per wave
#define NQ 8                         // float4 loads per lane per wave

// ---------------------------------------------------------------------------
// Exclusive block-wide scan of one unsigned per thread (tid order).
// ---------------------------------------------------------------------------
__device__ __forceinline__ unsigned block_excl_scan(unsigned tsum, unsigned* wtot) {
    const int lane = threadIdx.x & 63;
    const int wid  = threadIdx.x >> 6;
    unsigned v = tsum;
#pragma unroll
    for (int off = 1; off < 64; off <<= 1) {
        unsigned u = __shfl_up(v, off, 64);
        if (lane >= off) v += u;
    }
    if (lane == 63) wtot[wid] = v;
    __syncthreads();
    unsigned woff = 0;
    for (int w = 0; w < wid; ++w) woff += wtot[w];
    return woff + v - tsum;   // exclusive prefix for this thread
}

// ---------------------------------------------------------------------------
// Pass 1: wave-coalesced score read. Load q, lane i covers elements
// wbase + 256q + 4i .. +4. Nibbles are OR-merged across 8-lane groups into
// 32-element mask words stored in GLOBAL ELEMENT ORDER:
//   mask word g covers elements [32g, 32g+32).
// ---------------------------------------------------------------------------
__global__ void k_count(const float* __restrict__ score,
                        unsigned* __restrict__ blockCount,
                        unsigned* __restrict__ mask, long n) {
    const int  tid  = threadIdx.x;
    const int  lane = tid & 63, w = tid >> 6;
    const long base  = (long)blockIdx.x * CHUNK;
    const long wbase = base + (long)w * WCHUNK;
    unsigned cnt = 0;

    if (base + CHUNK <= n) {
        const float4* s4 = reinterpret_cast<const float4*>(score);
#pragma unroll
        for (int q = 0; q < NQ; ++q) {
            float4 v = s4[wbase / 4 + 64 * q + lane];
            unsigned nib = (unsigned)(v.x > 0.f)        | ((unsigned)(v.y > 0.f) << 1)
                         | ((unsigned)(v.z > 0.f) << 2) | ((unsigned)(v.w > 0.f) << 3);
            cnt += __popc(nib);
            unsigned part = nib << ((lane & 7) * 4);
            part |= __shfl_xor(part, 1);
            part |= __shfl_xor(part, 2);
            part |= __shfl_xor(part, 4);
            if ((lane & 7) == 0 && mask)
                mask[(wbase >> 5) + 8 * q + (lane >> 3)] = part;
        }
    } else {
        for (int q = 0; q < NQ; ++q) {
            unsigned nib = 0;
#pragma unroll
            for (int j = 0; j < 4; ++j) {
                long gi = wbase + 256 * q + 4 * lane + j;
                if (gi < n && score[gi] > 0.f) nib |= (1u << j);
            }
            cnt += __popc(nib);
            unsigned part = nib << ((lane & 7) * 4);
            part |= __shfl_xor(part, 1);
            part |= __shfl_xor(part, 2);
            part |= __shfl_xor(part, 4);
            if ((lane & 7) == 0 && mask)
                mask[(wbase >> 5) + 8 * q + (lane >> 3)] = part;
        }
    }

#pragma unroll
    for (int off = 32; off > 0; off >>= 1) cnt += __shfl_down(cnt, off, 64);
    __shared__ unsigned wsum[TPB / 64];
    if (lane == 0) wsum[w] = cnt;
    __syncthreads();
    if (tid == 0) {
        unsigned tot = 0;
        for (int i = 0; i < TPB / 64; ++i) tot += wsum[i];
        blockCount[blockIdx.x] = tot;
    }
}

// ---------------------------------------------------------------------------
// Pass 2: thread tid's mask word = elements [base + 32*tid, +32) -> the
// existing block scan is unchanged. Compute loop uses wave-coalesced float4
// predict loads; per load q, lane i fetches its word + block-prefix from
// lane (8q + i/8) via shfl. No fences, no atomics (rounds 3/5/6 lessons).
// ---------------------------------------------------------------------------
template <bool USE_MASK>
__global__ void k_main(const float* __restrict__ predict,
                       const float* __restrict__ score,
                       const unsigned* __restrict__ mask,
                       const unsigned* __restrict__ blockCount,
                       double* __restrict__ blockSum, long n, int B) {
    const int  tid  = threadIdx.x;
    const int  bid  = blockIdx.x;
    const int  lane = tid & 63, w = tid >> 6;
    const long base  = (long)bid * CHUNK;
    const long wbase = base + (long)w * WCHUNK;
    const bool full  = (base + CHUNK <= n);

    __shared__ unsigned wtot[TPB / 64];
    __shared__ unsigned wpart[2 * (TPB / 64)];
    __shared__ unsigned s_off, s_P;
    __shared__ double   dsum[TPB / 64];

    // --- this thread's mask word (its 32 contiguous elements) ---
    unsigned wd = 0;
    if (USE_MASK) {
        wd = mask[(size_t)bid * TPB + tid];
    } else {
        const long tb = base + (long)tid * PER_THREAD;
        if (tb + PER_THREAD <= n) {
            const float4* s4 = reinterpret_cast<const float4*>(score + tb);
#pragma unroll
            for (int q = 0; q < PER_THREAD / 4; ++q) {
                float4 v = s4[q];
                wd |= ((unsigned)(v.x > 0.f)) << (4 * q + 0);
                wd |= ((unsigned)(v.y > 0.f)) << (4 * q + 1);
                wd |= ((unsigned)(v.z > 0.f)) << (4 * q + 2);
                wd |= ((unsigned)(v.w > 0.f)) << (4 * q + 3);
            }
        } else {
            for (int e = 0; e < PER_THREAD; ++e) {
                long gi = tb + e;
                if (gi < n && score[gi] > 0.f) wd |= (1u << e);
            }
        }
    }

    unsigned cnt  = __popc(wd);
    unsigned excl = block_excl_scan(cnt, wtot);

    // --- per-block exclusive offset + global total P from blockCount ---
    unsigned offp = 0, tot = 0;
    for (int j = tid; j < B; j += TPB) {
        unsigned c = blockCount[j];
        tot  += c;
        offp += (j < bid) ? c : 0u;
    }
#pragma unroll
    for (int off = 32; off > 0; off >>= 1) {
        offp += __shfl_down(offp, off, 64);
        tot  += __shfl_down(tot,  off, 64);
    }
    if (lane == 0) { wpart[2 * w] = offp; wpart[2 * w + 1] = tot; }
    __syncthreads();
    if (tid == 0) {
        unsigned o = 0, t = 0;
        for (int i = 0; i < TPB / 64; ++i) { o += wpart[2 * i]; t += wpart[2 * i + 1]; }
        s_off = o; s_P = t;
    }
    __syncthreads();

    const unsigned P = s_P;
    const float invS = 1.0f / (float)P;                 // s value at positives
    const float sumS = (float)((double)invS * (double)P);
    const float rcpSumS = 1.0f / sumS;
    const float Pf = (float)P;

    const unsigned pre = s_off + excl;   // positives before this thread's word

    double acc = 0.0;
    if (full) {
        const float4* p4 = reinterpret_cast<const float4*>(predict);
#pragma unroll
        for (int q = 0; q < NQ; ++q) {
            const int t = 8 * q + (lane >> 3);
            const unsigned wq  = __shfl(wd,  t, 64);
            const unsigned prq = __shfl(pre, t, 64);
            const int nibStart = (lane & 7) * 4;
            unsigned run = prq + __popc(wq & ((1u << nibStart) - 1u));
            const unsigned nib = (wq >> nibStart) & 0xFu;
            float4 pv4 = p4[wbase / 4 + 64 * q + lane];
            float pv[4] = {pv4.x, pv4.y, pv4.z, pv4.w};
#pragma unroll
            for (int j = 0; j < 4; ++j) {
                const bool ispos = (nib >> j) & 1u;
                const unsigned newrun = run + (ispos ? 1u : 0u);
                const long gi = wbase + 256 * q + 4 * lane + j;
                const float p = pv[j] * rcpSumS;
                const float kp1  = (float)(newrun + 1u);
                const float posv = p * __builtin_amdgcn_rcpf(kp1)
                                 - invS * __builtin_amdgcn_rcpf(__log2f(kp1));
                const unsigned mr = (unsigned)(gi + 1) - newrun;
                const float negv  = p * __builtin_amdgcn_rcpf(Pf + (float)mr + 1.0f);
                const float tt = ispos ? posv : negv;
                acc += (double)(tt * tt);
                run = newrun;
            }
        }
    } else {
        for (int q = 0; q < NQ; ++q) {
            const int t = 8 * q + (lane >> 3);
            const unsigned wq  = __shfl(wd,  t, 64);
            const unsigned prq = __shfl(pre, t, 64);
            const int nibStart = (lane & 7) * 4;
            unsigned run = prq + __popc(wq & ((1u << nibStart) - 1u));
            const unsigned nib = (wq >> nibStart) & 0xFu;
            for (int j = 0; j < 4; ++j) {
                const long gi = wbase + 256 * q + 4 * lane + j;
                if (gi >= n) continue;
                const bool ispos = (nib >> j) & 1u;
                const unsigned newrun = run + (ispos ? 1u : 0u);
                const float p = predict[gi] * rcpSumS;
                const float kp1  = (float)(newrun + 1u);
                const float posv = p * __builtin_amdgcn_rcpf(kp1)
                                 - invS * __builtin_amdgcn_rcpf(__log2f(kp1));
                const unsigned mr = (unsigned)(gi + 1) - newrun;
                const float negv  = p * __builtin_amdgcn_rcpf(Pf + (float)mr + 1.0f);
                const float tt = ispos ? posv : negv;
                acc += (double)(tt * tt);
                run = newrun;
            }
        }
    }

    // --- deterministic block reduce ---
#pragma unroll
    for (int off = 32; off > 0; off >>= 1) acc += __shfl_down(acc, off, 64);
    if (lane == 0) dsum[w] = acc;
    __syncthreads();
    if (tid == 0) {
        double t = 0.0;
        for (int i = 0; i < TPB / 64; ++i) t += dsum[i];
        blockSum[bid] = t;
    }
}

// ---------------------------------------------------------------------------
// Pass 3: deterministic reduce of per-block doubles -> float scalar.
// ---------------------------------------------------------------------------
__global__ void k_final(const double* __restrict__ blockSum,
                        float* __restrict__ out, int B) {
    const int tid = threadIdx.x;
    double acc = 0.0;
    for (int j = tid; j < B; j += TPB) acc += blockSum[j];
#pragma unroll
    for (int off = 32; off > 0; off >>= 1) acc += __shfl_down(acc, off, 64);
    __shared__ double dsum[TPB / 64];
    const int lane = tid & 63, wid = tid >> 6;
    if (lane == 0) dsum[wid] = acc;
    __syncthreads();
    if (tid == 0) {
        double tot = 0.0;
        for (int w = 0; w < TPB / 64; ++w) tot += dsum[w];
        out[0] = (float)tot;
    }
}

extern "C" void kernel_launch(void* const* d_in, const int* in_sizes, int n_in,
                              void* d_out, int out_size, void* d_ws, size_t ws_size,
                              hipStream_t stream) {
    const float* predict = (const float*)d_in[0];
    const float* score   = (const float*)d_in[1];
    const long n = (long)in_sizes[0];
    const int B = (int)((n + CHUNK - 1) / CHUNK);   // 2048 for N=2^24

    unsigned char* ws = (unsigned char*)d_ws;
    size_t off = 0;
    unsigned* blockCount = (unsigned*)(ws + off); off += (size_t)B * sizeof(unsigned);
    off = (off + 255) & ~(size_t)255;
    double*   blockSum   = (double*)(ws + off);   off += (size_t)B * sizeof(double);
    off = (off + 255) & ~(size_t)255;
    unsigned* maskBuf    = (unsigned*)(ws + off);
    const size_t maskBytes = (size_t)B * TPB * sizeof(unsigned);
    const bool useMask = (off + maskBytes) <= ws_size;

    k_count<<<B, TPB, 0, stream>>>(score, blockCount, useMask ? maskBuf : nullptr, n);
    if (useMask)
        k_main<true><<<B, TPB, 0, stream>>>(predict, nullptr, maskBuf, blockCount,
                                            blockSum, n, B);
    else
        k_main<false><<<B, TPB, 0, stream>>>(predict, score, nullptr, blockCount,
                                             blockSum, n, B);
    k_final<<<1, TPB, 0, stream>>>(blockSum, (float*)d_out, B);
}